// Round 21
// baseline (601.088 us; speedup 1.0000x reference)
//
#include <hip/hip_runtime.h>
#include <hip/hip_fp16.h>
#include <math.h>

// Problem constants: B=8, Tt=16, C=1, H=W=512, 4 in-channels, 10 T-planes.
#define Bd 8
#define Td 16
#define Hd 512
#define Wd 512
#define HWc (Hd * Wd)          // 262144
#define NPIX (Bd * HWc)        // 2,097,152

// ---------------- conv tiling: 16x16 tile, 1 px/thread, 256 threads ----------
#define CT  16
#define CR  18
#define CP  20
#define CTH2 256

// ---------------- fused kernel: 64x64 core, halo 6, 2 blocks/CU --------------
#define WCR 64                 // core rows
#define WCC 64                 // core cols
#define WH  6                  // halo
#define WTR 76                 // region rows
#define WTC 76                 // region cols
#define WLP 77                 // LDS row pitch
#define WTHR 512               // 8 waves -> 2 blocks/CU co-resident
#define WRPG 13                // owned rows per thread
#define WNG 6                  // row groups (6*13 = 78 >= 74 interior rows)

// v_fma_mix_f32: acc(f32) += w(f32) * h.lo/h.hi(f16) in ONE instruction.
#define FMAMIX_LO(acc, wv, hv) \
    asm("v_fma_mix_f32 %0, %1, %2, %0 op_sel:[0,0,0] op_sel_hi:[0,1,0]" \
        : "+v"(acc) : "v"(wv), "v"(hv))
#define FMAMIX_HI(acc, wv, hv) \
    asm("v_fma_mix_f32 %0, %1, %2, %0 op_sel:[0,1,0] op_sel_hi:[0,1,0]" \
        : "+v"(acc) : "v"(wv), "v"(hv))

__device__ __forceinline__ float hi_half_f32(unsigned h) {
    __half2 hh = *(__half2*)&h;
    return __half2float(__high2half(hh));
}

// ---------------------------------------------------------------------------
// Kernel 1 (r17 proven): o-outer conv, 1 px/thread, contiguous weight loads.
// T = conv2d(x[:,-4:,0],W)+b fused with xt0 -> out[:,0].
// T stored as half2 pairs: plane q holds (T[2q], T[2q+1]); layout (B,5,H,W).
// ---------------------------------------------------------------------------
__global__ __launch_bounds__(CTH2)
void conv_step0_kernel(const float* __restrict__ x,
                       const float* __restrict__ Wu,
                       const float* __restrict__ bu,
                       __half2* __restrict__ T,
                       float* __restrict__ out) {
    __shared__ float sX[4][CR][CP];     // 5.76 KB

    int bx  = blockIdx.x;               // 8192 = 8 b * 32 * 32 tiles
    int b   = bx >> 10;
    int rem = bx & 1023;
    int by  = rem >> 5;
    int bc  = rem & 31;
    int i0  = by * CT;
    int j0  = bc * CT;

    const float* xb = x + ((size_t)b * Td + 12) * HWc;
    int tid = threadIdx.x;

    for (int idx = tid; idx < 4 * CR * CR; idx += CTH2) {
        int ch = idx / (CR * CR);
        int r2 = idx - ch * (CR * CR);
        int r  = r2 / CR;
        int c  = r2 - r * CR;
        int gi = i0 + r - 1, gj = j0 + c - 1;
        float v = 0.0f;
        if ((unsigned)gi < (unsigned)Hd && (unsigned)gj < (unsigned)Wd)
            v = xb[(size_t)ch * HWc + gi * Wd + gj];
        sX[ch][r][c] = v;
    }
    __syncthreads();

    int tx = tid & 15;
    int ty = tid >> 4;

    float xf[36];
    #pragma unroll
    for (int ch = 0; ch < 4; ++ch)
        #pragma unroll
        for (int kh = 0; kh < 3; ++kh)
            #pragma unroll
            for (int kw = 0; kw < 3; ++kw)
                xf[(ch * 3 + kh) * 3 + kw] = sX[ch][ty + kh][tx + kw];

    int gi = i0 + ty;
    int gj = j0 + tx;
    size_t pix = (size_t)gi * Wd + gj;
    __half2* Tb = T + (size_t)b * 5 * HWc;

    float o0 = 0.0f;
    float accPrev = 0.0f;
    #pragma unroll
    for (int o = 0; o < 10; ++o) {
        const float* wo = Wu + o * 36;  // contiguous -> batched s_load
        float acc = bu[o];
        #pragma unroll
        for (int z = 0; z < 36; ++z)
            acc += xf[z] * wo[z];

        // step0 inline: k = dj*3+di multiplies x15[i+di-1, j+dj-1].
        if (o < 9)
            o0 += xf[(3 * 3 + (o % 3)) * 3 + (o / 3)] * acc;
        else
            o0 += acc;

        if (o & 1) {
            __half2 h = __floats2half2_rn(accPrev, acc);
            *(unsigned*)(Tb + (size_t)(o >> 1) * HWc + pix) = *(unsigned*)&h;
        }
        accPrev = acc;
    }

    out[(size_t)b * Td * HWc + pix] = o0;
}

// ---------------------------------------------------------------------------
// Kernel 2 (r19 wide kernel, geometry halved for 2 blocks/CU): one scan-body
// iteration = 6 fused stencil steps, 64x64 core (region 76x76), 512 blocks =
// 2 blocks/CU so block B's T-load overlaps block A's compute. Thread owns
// column c = tid%76, rows rs..rs+12; 65 half2 T coefs in VGPRs (fma_mix
// taps); x ping-pongs in LDS (2 x 23.4 KB). Sigmoid at even sub-steps. Ring
// never written; contamination <=1 px/step; halo 6 protects the core. Step 6
// stores the core directly to global (after 5 swaps cur = step-5 state).
// ---------------------------------------------------------------------------
__global__ __launch_bounds__(WTHR, 2)
void fused6_wide_kernel(const float* __restrict__ xin,   // out slot t-1 base
                        const __half2* __restrict__ T,
                        float* __restrict__ xout) {      // out slot t base
    __shared__ float sA[WTR * WLP];
    __shared__ float sB[WTR * WLP];

    int tile = blockIdx.x;          // 512 = 8 b * 8 tr * 8 tc
    int b  = tile >> 6;
    int tr = (tile >> 3) & 7;
    int tc = tile & 7;
    int ri = tr * WCR - WH;
    int rj = tc * WCC - WH;

    const float* xb = xin + (size_t)b * Td * HWc;
    const __half2* Tb = T + (size_t)b * 5 * HWc;
    float* ob = xout + (size_t)b * Td * HWc;
    int tid = threadIdx.x;

    // Stage sA (zeros outside image).
    for (int idx = tid; idx < WTR * WTC; idx += WTHR) {
        int r = idx / WTC, c = idx - r * WTC;
        int gi = ri + r, gj = rj + c;
        float v = 0.0f;
        if ((unsigned)gi < (unsigned)Hd && (unsigned)gj < (unsigned)Wd)
            v = xb[gi * Wd + gj];
        sA[r * WLP + c] = v;
    }
    // Zero only sB's ring (never written by the step loop; interior fully
    // rewritten each step before being read).
    for (int idx = tid; idx < 2 * WTC; idx += WTHR) {
        int r = (idx < WTC) ? 0 : (WTR - 1);
        int c = (idx < WTC) ? idx : idx - WTC;
        sB[r * WLP + c] = 0.0f;
    }
    for (int idx = tid; idx < 2 * WTR; idx += WTHR) {
        int r = (idx < WTR) ? idx : idx - WTR;
        int c = (idx < WTR) ? 0 : (WTC - 1);
        sB[r * WLP + c] = 0.0f;
    }

    int g  = tid / WTC;             // row group 0..5 valid
    int c  = tid - g * WTC;         // column 0..75
    int rs = 1 + g * WRPG;          // first owned row (1..66)
    bool colint = (c >= 1) && (c <= WTC - 2);
    bool active = (g < WNG) && colint;
    int  gj     = rj + c;
    bool colin  = (unsigned)gj < (unsigned)Wd;
    bool colcore = (c >= WH) && (c <= WTC - 1 - WH);   // core column

    // T coefficients: 5 half2 (raw u32) per owned row.
    unsigned treg[WRPG][5];
    #pragma unroll
    for (int jj = 0; jj < WRPG; ++jj) {
        int r  = rs + jj;
        int gi = ri + r;
        bool ok = active && (r <= WTR - 2) && ((unsigned)gi < (unsigned)Hd) && colin;
        #pragma unroll
        for (int q = 0; q < 5; ++q) {
            unsigned v = 0u;
            if (ok) v = *(const unsigned*)(Tb + (size_t)q * HWc + gi * Wd + gj);
            treg[jj][q] = v;
        }
    }
    __syncthreads();

    float* cur = sA;
    float* nxt = sB;

    #pragma unroll
    for (int s = 1; s <= 6; ++s) {
        if (active) {
            float w00 = cur[(rs - 1) * WLP + c - 1];
            float w01 = cur[(rs - 1) * WLP + c];
            float w02 = cur[(rs - 1) * WLP + c + 1];
            float w10 = cur[rs * WLP + c - 1];
            float w11 = cur[rs * WLP + c];
            float w12 = cur[rs * WLP + c + 1];
            #pragma unroll
            for (int jj = 0; jj < WRPG; ++jj) {
                int r  = rs + jj;
                int r2 = (r + 1 <= WTR - 1) ? (r + 1) : (WTR - 1);  // clamp tail
                float w20 = cur[r2 * WLP + c - 1];
                float w21 = cur[r2 * WLP + c];
                float w22 = cur[r2 * WLP + c + 1];

                unsigned h0 = treg[jj][0], h1 = treg[jj][1], h2 = treg[jj][2],
                         h3 = treg[jj][3], h4 = treg[jj][4];
                // k = dj*3+di multiplies x[r+di-1][c+dj-1]
                float a = hi_half_f32(h4);      // T9
                FMAMIX_LO(a, w00, h0);
                FMAMIX_HI(a, w10, h0);
                FMAMIX_LO(a, w20, h1);
                FMAMIX_HI(a, w01, h1);
                FMAMIX_LO(a, w11, h2);
                FMAMIX_HI(a, w21, h2);
                FMAMIX_LO(a, w02, h3);
                FMAMIX_HI(a, w12, h3);
                FMAMIX_LO(a, w22, h4);
                if ((s & 1) == 0) a = 1.0f / (1.0f + __expf(-a));

                int gi = ri + r;
                if (s < 6) {
                    bool rowok = (r <= WTR - 2);
                    bool inimg = ((unsigned)gi < (unsigned)Hd) && colin;
                    if (rowok) nxt[r * WLP + c] = inimg ? a : 0.0f;
                } else {
                    // Direct global store of the core (always in-image).
                    if (colcore && r >= WH && r <= WTR - 1 - WH)
                        ob[gi * Wd + gj] = a;
                }

                w00 = w10; w01 = w11; w02 = w12;
                w10 = w20; w11 = w21; w12 = w22;
            }
        }
        if (s < 6) {
            __syncthreads();
            float* tmp = cur; cur = nxt; nxt = tmp;
        }
    }
}

// ---------------------------------------------------------------------------
// Workspace: T only (B*5*H*W half2 = 40 MB).
// ---------------------------------------------------------------------------
extern "C" void kernel_launch(void* const* d_in, const int* in_sizes, int n_in,
                              void* d_out, int out_size, void* d_ws, size_t ws_size,
                              hipStream_t stream) {
    const float* x  = (const float*)d_in[0];
    const float* Wu = (const float*)d_in[1];
    const float* bu = (const float*)d_in[2];
    float* out = (float*)d_out;
    __half2* T = (__half2*)d_ws;

    conv_step0_kernel<<<8192, CTH2, 0, stream>>>(x, Wu, bu, T, out);

    for (int t = 1; t < Td; ++t)
        fused6_wide_kernel<<<512, WTHR, 0, stream>>>(out + (size_t)(t - 1) * HWc, T,
                                                     out + (size_t)t * HWc);
}

// Round 22
// 479.527 us; speedup vs baseline: 1.2535x; 1.2535x over previous
//
#include <hip/hip_runtime.h>
#include <hip/hip_fp16.h>
#include <math.h>

// Problem constants: B=8, Tt=16, C=1, H=W=512, 4 in-channels, 10 T-planes.
#define Bd 8
#define Td 16
#define Hd 512
#define Wd 512
#define HWc (Hd * Wd)          // 262144
#define NPIX (Bd * HWc)        // 2,097,152

// ---------------- conv tiling: 16x16 tile, 1 px/thread, 256 threads ----------
#define CT  16
#define CR  18
#define CP  20
#define CTH2 256

// ---------------- fused kernel: 128x64 core, halo 6, fp32 col-pairs ----------
#define WCR 128                // core rows
#define WCC 64                 // core cols
#define WH  6                  // halo
#define WTR 140                // region rows
#define WTC 76                 // region cols = 38 pairs
#define NPR 38                 // column pairs
#define WP2 78                 // LDS row pitch in floats (EVEN for b64 align)
#define FTH 1024
#define PRPG 6                 // owned rows per thread
#define PNG 26                 // row groups (26*6 = 156 >= 138 interior rows)

// v_fma_mix_f32: acc(f32) += w(f32) * h.lo/h.hi(f16) in ONE instruction.
#define FMAMIX_LO(acc, wv, hv) \
    asm("v_fma_mix_f32 %0, %1, %2, %0 op_sel:[0,0,0] op_sel_hi:[0,1,0]" \
        : "+v"(acc) : "v"(wv), "v"(hv))
#define FMAMIX_HI(acc, wv, hv) \
    asm("v_fma_mix_f32 %0, %1, %2, %0 op_sel:[0,1,0] op_sel_hi:[0,1,0]" \
        : "+v"(acc) : "v"(wv), "v"(hv))

__device__ __forceinline__ float hi_half_f32(unsigned h) {
    __half2 hh = *(__half2*)&h;
    return __half2float(__high2half(hh));
}

// ---------------------------------------------------------------------------
// Kernel 1 (r17 proven): o-outer conv, 1 px/thread, contiguous weight loads.
// T = conv2d(x[:,-4:,0],W)+b fused with xt0 -> out[:,0].
// T stored as half2 pairs: plane q holds (T[2q], T[2q+1]); layout (B,5,H,W).
// ---------------------------------------------------------------------------
__global__ __launch_bounds__(CTH2)
void conv_step0_kernel(const float* __restrict__ x,
                       const float* __restrict__ Wu,
                       const float* __restrict__ bu,
                       __half2* __restrict__ T,
                       float* __restrict__ out) {
    __shared__ float sX[4][CR][CP];     // 5.76 KB

    int bx  = blockIdx.x;               // 8192 = 8 b * 32 * 32 tiles
    int b   = bx >> 10;
    int rem = bx & 1023;
    int by  = rem >> 5;
    int bc  = rem & 31;
    int i0  = by * CT;
    int j0  = bc * CT;

    const float* xb = x + ((size_t)b * Td + 12) * HWc;
    int tid = threadIdx.x;

    for (int idx = tid; idx < 4 * CR * CR; idx += CTH2) {
        int ch = idx / (CR * CR);
        int r2 = idx - ch * (CR * CR);
        int r  = r2 / CR;
        int c  = r2 - r * CR;
        int gi = i0 + r - 1, gj = j0 + c - 1;
        float v = 0.0f;
        if ((unsigned)gi < (unsigned)Hd && (unsigned)gj < (unsigned)Wd)
            v = xb[(size_t)ch * HWc + gi * Wd + gj];
        sX[ch][r][c] = v;
    }
    __syncthreads();

    int tx = tid & 15;
    int ty = tid >> 4;

    float xf[36];
    #pragma unroll
    for (int ch = 0; ch < 4; ++ch)
        #pragma unroll
        for (int kh = 0; kh < 3; ++kh)
            #pragma unroll
            for (int kw = 0; kw < 3; ++kw)
                xf[(ch * 3 + kh) * 3 + kw] = sX[ch][ty + kh][tx + kw];

    int gi = i0 + ty;
    int gj = j0 + tx;
    size_t pix = (size_t)gi * Wd + gj;
    __half2* Tb = T + (size_t)b * 5 * HWc;

    float o0 = 0.0f;
    float accPrev = 0.0f;
    #pragma unroll
    for (int o = 0; o < 10; ++o) {
        const float* wo = Wu + o * 36;  // contiguous -> batched s_load
        float acc = bu[o];
        #pragma unroll
        for (int z = 0; z < 36; ++z)
            acc += xf[z] * wo[z];

        // step0 inline: k = dj*3+di multiplies x15[i+di-1, j+dj-1].
        if (o < 9)
            o0 += xf[(3 * 3 + (o % 3)) * 3 + (o / 3)] * acc;
        else
            o0 += acc;

        if (o & 1) {
            __half2 h = __floats2half2_rn(accPrev, acc);
            *(unsigned*)(Tb + (size_t)(o >> 1) * HWc + pix) = *(unsigned*)&h;
        }
        accPrev = acc;
    }

    out[(size_t)b * Td * HWc + pix] = o0;
}

// ---------------------------------------------------------------------------
// Kernel 2: one scan-body iteration = 6 fused stencil steps, 128x64 core
// (region 140x76, pitch 78), fp32 LDS state with 2-COLUMN-PAIR ownership:
// thread owns cols (2u, 2u+1) x 6 rows; per row the window cols 2u-1..2u+2
// are 1 scalar + 1 aligned float2 + 1 scalar LDS read (3 ops / 2 px), write
// is one float2 (edge pairs write their single interior col). T (30 half2
// per col-pair) in VGPRs, fma_mix taps -> numerics identical to r19.
// Sigmoid at even sub-steps; ring never written; contamination <=1 px/step;
// halo 6 protects the core; out-of-image px forced 0. Step 6 stores the core
// directly to global as float2. 256 blocks = 1/CU, one round. (1024,2) ->
// 128-VGPR cap; demand ~92 -> no spill.
// ---------------------------------------------------------------------------
__global__ __launch_bounds__(FTH, 2)
void fused6_pair32_kernel(const float* __restrict__ xin,   // out slot t-1 base
                          const __half2* __restrict__ T,
                          float* __restrict__ xout) {      // out slot t base
    __shared__ __align__(16) float sA[WTR * WP2];   // 43.7 KB
    __shared__ __align__(16) float sB[WTR * WP2];

    int tile = blockIdx.x;          // 256 = 8 b * 4 tr * 8 tc
    int b  = tile >> 5;
    int tr = (tile >> 3) & 3;
    int tc = tile & 7;
    int ri = tr * WCR - WH;
    int rj = tc * WCC - WH;         // even

    const float* xb = xin + (size_t)b * Td * HWc;
    const __half2* Tb = T + (size_t)b * 5 * HWc;
    float* ob = xout + (size_t)b * Td * HWc;
    int tid = threadIdx.x;

    // Stage sA by pairs (float2 global loads; pairs never straddle the image
    // edge since rj and 512 are both even). Zeros outside image.
    for (int idx = tid; idx < WTR * NPR; idx += FTH) {
        int r = idx / NPR, u = idx - r * NPR;
        int gi = ri + r, gj0 = rj + 2 * u;
        float v0 = 0.0f, v1 = 0.0f;
        if ((unsigned)gi < (unsigned)Hd && (unsigned)gj0 < (unsigned)Wd) {
            float2 f = *(const float2*)(xb + gi * Wd + gj0);
            v0 = f.x; v1 = f.y;
        }
        float2 st; st.x = v0; st.y = v1;
        *(float2*)&sA[r * WP2 + 2 * u] = st;
    }
    // Zero sB's ring: rows 0/139 fully; cols 0 and 75 on every row.
    for (int idx = tid; idx < 2 * WTC; idx += FTH) {
        int r = (idx < WTC) ? 0 : (WTR - 1);
        int c = (idx < WTC) ? idx : idx - WTC;
        sB[r * WP2 + c] = 0.0f;
    }
    for (int idx = tid; idx < 2 * WTR; idx += FTH) {
        int r = (idx < WTR) ? idx : idx - WTR;
        int c = (idx < WTR) ? 0 : (WTC - 1);
        sB[r * WP2 + c] = 0.0f;
    }

    int g = tid / NPR;              // row group (0..25 active)
    int u = tid - g * NPR;          // pair index 0..37
    bool active = (g < PNG);
    int rs = 1 + g * PRPG;          // first owned row (1..151; rows >138 masked)
    int c0 = 2 * u;
    int gj0 = rj + c0;
    bool pairin = (unsigned)gj0 < (unsigned)Wd;    // pair fully in-image
    int offL = (u == 0) ? 0 : (c0 - 1);            // clamped; feeds ring only
    int offR = (u == NPR - 1) ? (WTC - 1) : (c0 + 2);

    // T coefs: uint2 = both pixels' half2 per plane per row (8B aligned).
    unsigned tA[PRPG][5], tB[PRPG][5];
    #pragma unroll
    for (int jj = 0; jj < PRPG; ++jj) {
        int r  = rs + jj;
        int gi = ri + r;
        bool ok = active && (r <= WTR - 2) && ((unsigned)gi < (unsigned)Hd) && pairin;
        #pragma unroll
        for (int q = 0; q < 5; ++q) {
            uint2 pk; pk.x = 0u; pk.y = 0u;
            if (ok) pk = *(const uint2*)(Tb + (size_t)q * HWc + gi * Wd + gj0);
            tA[jj][q] = pk.x;
            tB[jj][q] = pk.y;
        }
    }
    __syncthreads();

    float* cur = sA;
    float* nxt = sB;

    #pragma unroll
    for (int s = 1; s <= 6; ++s) {
        if (active) {
            // Streaming 3-row window: L = col c0-1, M = cols (c0, c0+1),
            // R = col c0+2.
            int base = (rs - 1) * WP2;
            float  Lp = cur[base + offL];
            float2 Mp = *(const float2*)&cur[base + c0];
            float  Rp = cur[base + offR];
            base += WP2;
            float  Lc = cur[base + offL];
            float2 Mc = *(const float2*)&cur[base + c0];
            float  Rc = cur[base + offR];
            #pragma unroll
            for (int jj = 0; jj < PRPG; ++jj) {
                int r  = rs + jj;
                int rn = (r + 1 <= WTR - 1) ? (r + 1) : (WTR - 1);
                int bn = rn * WP2;
                float  Ln = cur[bn + offL];
                float2 Mn = *(const float2*)&cur[bn + c0];
                float  Rn = cur[bn + offR];

                // k = dj*3+di multiplies x[r+di-1][c+dj-1].
                // px0 (col c0): taps L (dj0), M.x (dj1), M.y (dj2).
                float a0 = hi_half_f32(tA[jj][4]);     // T9
                FMAMIX_LO(a0, Lp,   tA[jj][0]);        // k0
                FMAMIX_HI(a0, Lc,   tA[jj][0]);        // k1
                FMAMIX_LO(a0, Ln,   tA[jj][1]);        // k2
                FMAMIX_HI(a0, Mp.x, tA[jj][1]);        // k3
                FMAMIX_LO(a0, Mc.x, tA[jj][2]);        // k4
                FMAMIX_HI(a0, Mn.x, tA[jj][2]);        // k5
                FMAMIX_LO(a0, Mp.y, tA[jj][3]);        // k6
                FMAMIX_HI(a0, Mc.y, tA[jj][3]);        // k7
                FMAMIX_LO(a0, Mn.y, tA[jj][4]);        // k8
                // px1 (col c0+1): taps M.x (dj0), M.y (dj1), R (dj2).
                float a1 = hi_half_f32(tB[jj][4]);     // T9
                FMAMIX_LO(a1, Mp.x, tB[jj][0]);        // k0
                FMAMIX_HI(a1, Mc.x, tB[jj][0]);        // k1
                FMAMIX_LO(a1, Mn.x, tB[jj][1]);        // k2
                FMAMIX_HI(a1, Mp.y, tB[jj][1]);        // k3
                FMAMIX_LO(a1, Mc.y, tB[jj][2]);        // k4
                FMAMIX_HI(a1, Mn.y, tB[jj][2]);        // k5
                FMAMIX_LO(a1, Rp,   tB[jj][3]);        // k6
                FMAMIX_HI(a1, Rc,   tB[jj][3]);        // k7
                FMAMIX_LO(a1, Rn,   tB[jj][4]);        // k8

                if ((s & 1) == 0) {
                    a0 = 1.0f / (1.0f + __expf(-a0));
                    a1 = 1.0f / (1.0f + __expf(-a1));
                }

                int gi = ri + r;
                bool inimg = ((unsigned)gi < (unsigned)Hd) && pairin;
                float v0 = inimg ? a0 : 0.0f;
                float v1 = inimg ? a1 : 0.0f;

                if (s < 6) {
                    if (r <= WTR - 2) {
                        if (u >= 1 && u <= NPR - 2) {
                            float2 st; st.x = v0; st.y = v1;
                            *(float2*)&nxt[r * WP2 + c0] = st;
                        } else if (u == 0) {
                            nxt[r * WP2 + 1] = v1;       // col 0 is ring
                        } else {
                            nxt[r * WP2 + WTC - 2] = v0; // col 75 is ring
                        }
                    }
                } else {
                    // Direct global store of the core (pairs fully in-image).
                    if (u >= WH / 2 && u <= (WTC - 2 - WH) / 2 &&
                        r >= WH && r <= WTR - 1 - WH) {
                        float2 st; st.x = v0; st.y = v1;
                        *(float2*)(ob + gi * Wd + gj0) = st;
                    }
                }

                Lp = Lc; Mp = Mc; Rp = Rc;
                Lc = Ln; Mc = Mn; Rc = Rn;
            }
        }
        if (s < 6) {
            __syncthreads();
            float* tmp = cur; cur = nxt; nxt = tmp;
        }
    }
}

// ---------------------------------------------------------------------------
// Workspace: T only (B*5*H*W half2 = 40 MB).
// ---------------------------------------------------------------------------
extern "C" void kernel_launch(void* const* d_in, const int* in_sizes, int n_in,
                              void* d_out, int out_size, void* d_ws, size_t ws_size,
                              hipStream_t stream) {
    const float* x  = (const float*)d_in[0];
    const float* Wu = (const float*)d_in[1];
    const float* bu = (const float*)d_in[2];
    float* out = (float*)d_out;
    __half2* T = (__half2*)d_ws;

    conv_step0_kernel<<<8192, CTH2, 0, stream>>>(x, Wu, bu, T, out);

    for (int t = 1; t < Td; ++t)
        fused6_pair32_kernel<<<256, FTH, 0, stream>>>(out + (size_t)(t - 1) * HWc, T,
                                                      out + (size_t)t * HWc);
}